// Round 9
// baseline (90.092 us; speedup 1.0000x reference)
//
#include <hip/hip_runtime.h>

#define TWO_N 400
#define IN_C 32
#define OUT_C 32
#define NG 4
#define NB 512
#define K_TOT 128   // NG*IN_C

// MFMA fragment types: 8 bf16 in 4 VGPRs; 4 fp32 acc.
typedef __attribute__((ext_vector_type(8))) short bf16x8;
typedef __attribute__((ext_vector_type(4))) float f32x4;

// Round-to-nearest-even f32 -> bf16 (branchless).
static __device__ inline unsigned short f2bf(float f) {
    unsigned u = __float_as_uint(f);
    u = (u + 0x7FFFu + ((u >> 16) & 1u)) >> 16;
    return (unsigned short)u;
}

// Workspace layout (bytes): inv_t @ 0 (400*4 ints = 6400B), wt @ 8192 (8192B),
// xt @ 32768 (512*400*32*2 = 13107200B).
#define WS_WT_OFF   8192
#define WS_XT_OFF   32768

// ---------------------------------------------------------------------------
// Prep kernel: one launch, three block groups, all coalesced, no LDS.
//  blocks [0,800):    transpose+bf16  xt[b][i][c] = bf16(x[b][c][i])
//  blocks [800,3300): perm scan ->    inv_t[o*4+g] = i with perm[g,i,o]==1
//  blocks [3300,3316) w transpose ->  wt[d*128 + g*32 + c] = bf16(w[g][c][d])
// ---------------------------------------------------------------------------
__global__ __launch_bounds__(256) void prep_kernel(
        const float* __restrict__ x, const float* __restrict__ w,
        const float* __restrict__ perm,
        int* __restrict__ inv_t, unsigned short* __restrict__ wt,
        unsigned short* __restrict__ xt) {
    const int blk = blockIdx.x;
    const int t   = threadIdx.x;

    if (blk < 800) {                      // x transpose: one thread per (b,i)
        int tid = blk * 256 + t;          // [0, 204800)
        int b = tid / TWO_N;
        int i = tid - b * TWO_N;
        const float* xb = x + (size_t)b * IN_C * TWO_N + i;
        unsigned pk[16];
#pragma unroll
        for (int c2 = 0; c2 < 16; ++c2) { // reads: 256B contiguous per instr
            float v0 = xb[(size_t)(2 * c2) * TWO_N];
            float v1 = xb[(size_t)(2 * c2 + 1) * TWO_N];
            pk[c2] = (unsigned)f2bf(v0) | ((unsigned)f2bf(v1) << 16);
        }
        uint4* dst = (uint4*)(xt + (size_t)tid * 32);   // 64B row per thread
#pragma unroll
        for (int j = 0; j < 4; ++j) {
            uint4 u = {pk[4 * j], pk[4 * j + 1], pk[4 * j + 2], pk[4 * j + 3]};
            dst[j] = u;
        }
    } else if (blk < 3300) {              // perm scan, coalesced
        int tt = (blk - 800) * 256 + t;   // [0, 640000)
        float v = perm[tt];
        if (v > 0.5f) {
            int g = tt / (TWO_N * TWO_N);
            int rem = tt - g * (TWO_N * TWO_N);
            int i = rem / TWO_N;
            int o = rem - i * TWO_N;
            inv_t[o * 4 + g] = i;         // unique writer per slot
        }
    } else {                              // w transpose (4096 elems)
        int f = (blk - 3300) * 256 + t;   // f = g*1024 + c*32 + d
        int d = f & 31;
        int c = (f >> 5) & 31;
        int g = f >> 10;
        wt[d * K_TOT + g * 32 + c] = f2bf(w[f]);
    }
}

// ---------------------------------------------------------------------------
// Conv kernel: one block per b, 4 waves, NO LDS, no barrier.
//   out[b, d, o] = sum_{g,c} wt[d, g*32+c] * xt[b, inv_g(o), c]
// A-fragments preloaded to registers; B-fragments gathered from global xt
// (64B rows, 4 lanes/row -> full-line utilization, L1/L2 resident);
// inv_t int4 prefetched one iteration ahead; two independent MFMA chains.
// D layout: col(o)=lane&15, row(d)=(lane>>4)*4+j  [verified in R4 bench].
// ---------------------------------------------------------------------------
__global__ __launch_bounds__(256) void dihedral_conv_mfma(
        const int* __restrict__ inv_t,
        const unsigned short* __restrict__ wt,
        const unsigned short* __restrict__ xt,
        float* __restrict__ out) {
    const int b    = blockIdx.x;
    const int lane = threadIdx.x & 63;
    const int wid  = threadIdx.x >> 6;    // 0..3
    const int l15  = lane & 15;
    const int q    = lane >> 4;           // 0..3

    // Preload all 8 A fragments: afrag[dt][g] = wt[dt*16+l15][g*32 + q*8 ..]
    bf16x8 afrag[2][4];
#pragma unroll
    for (int dt = 0; dt < 2; ++dt)
#pragma unroll
        for (int g = 0; g < NG; ++g)
            afrag[dt][g] = *(const bf16x8*)(wt + (dt * 16 + l15) * K_TOT
                                               + g * 32 + q * 8);

    const unsigned short* xb = xt + (size_t)b * (TWO_N * IN_C);
    float* outb = out + (size_t)b * (OUT_C * TWO_N);

    int ot = wid;                          // 25 o-tiles split across 4 waves
    int4 iv = *(const int4*)(inv_t + (ot * 16 + l15) * 4);
    while (true) {
        int ot_n = ot + 4;
        bool has_n = (ot_n < 25);
        int4 iv_n;
        if (has_n)                         // prefetch next indices
            iv_n = *(const int4*)(inv_t + (ot_n * 16 + l15) * 4);

        // B fragments: gathered rows of xt[b] (16B per lane, 64B per row).
        bf16x8 b0 = *(const bf16x8*)(xb + iv.x * IN_C + q * 8);
        bf16x8 b1 = *(const bf16x8*)(xb + iv.y * IN_C + q * 8);
        bf16x8 b2 = *(const bf16x8*)(xb + iv.z * IN_C + q * 8);
        bf16x8 b3 = *(const bf16x8*)(xb + iv.w * IN_C + q * 8);

        f32x4 acc0 = {0.f, 0.f, 0.f, 0.f};
        f32x4 acc1 = {0.f, 0.f, 0.f, 0.f};
        acc0 = __builtin_amdgcn_mfma_f32_16x16x32_bf16(afrag[0][0], b0, acc0, 0, 0, 0);
        acc1 = __builtin_amdgcn_mfma_f32_16x16x32_bf16(afrag[1][0], b0, acc1, 0, 0, 0);
        acc0 = __builtin_amdgcn_mfma_f32_16x16x32_bf16(afrag[0][1], b1, acc0, 0, 0, 0);
        acc1 = __builtin_amdgcn_mfma_f32_16x16x32_bf16(afrag[1][1], b1, acc1, 0, 0, 0);
        acc0 = __builtin_amdgcn_mfma_f32_16x16x32_bf16(afrag[0][2], b2, acc0, 0, 0, 0);
        acc1 = __builtin_amdgcn_mfma_f32_16x16x32_bf16(afrag[1][2], b2, acc1, 0, 0, 0);
        acc0 = __builtin_amdgcn_mfma_f32_16x16x32_bf16(afrag[0][3], b3, acc0, 0, 0, 0);
        acc1 = __builtin_amdgcn_mfma_f32_16x16x32_bf16(afrag[1][3], b3, acc1, 0, 0, 0);

        // Stores: d = dt*16 + q*4 + j, o = ot*16 + l15.
        float* op0 = outb + (size_t)(q * 4) * TWO_N + ot * 16 + l15;
        float* op1 = op0 + (size_t)16 * TWO_N;
#pragma unroll
        for (int j = 0; j < 4; ++j) {
            __builtin_nontemporal_store(acc0[j], op0 + (size_t)j * TWO_N);
            __builtin_nontemporal_store(acc1[j], op1 + (size_t)j * TWO_N);
        }

        if (!has_n) break;
        ot = ot_n;
        iv = iv_n;
    }
}

extern "C" void kernel_launch(void* const* d_in, const int* in_sizes, int n_in,
                              void* d_out, int out_size, void* d_ws, size_t ws_size,
                              hipStream_t stream) {
    const float* x    = (const float*)d_in[0];  // [512, 32, 400]
    const float* w    = (const float*)d_in[1];  // [4, 32, 32]
    const float* perm = (const float*)d_in[2];  // [4, 400, 400]
    float* out = (float*)d_out;                 // [512, 32, 400]

    char* ws = (char*)d_ws;
    int*            inv_t = (int*)ws;
    unsigned short* wt    = (unsigned short*)(ws + WS_WT_OFF);
    unsigned short* xt    = (unsigned short*)(ws + WS_XT_OFF);

    prep_kernel<<<3316, 256, 0, stream>>>(x, w, perm, inv_t, wt, xt);
    dihedral_conv_mfma<<<NB, 256, 0, stream>>>(inv_t, wt, xt, out);
}